// Round 3
// baseline (178.231 us; speedup 1.0000x reference)
//
#include <hip/hip_runtime.h>
#include <math.h>

typedef __attribute__((ext_vector_type(8))) short s16x8;
typedef __attribute__((ext_vector_type(4))) float f32x4;

#define N_ROWS 2048
#define D_DIM  128
#define N_CLS  100000
#define N_TILES 782              // ceil(100000/128)
#define N_PAD   96.0f            // 782*128 - 100000 pad classes, each contributes exp(0)=1
#define S_SCALE 64.0f
#define S_LOG2E 92.33248261689366f   // 64 * log2(e)
#define EPS_F   1e-7f
#define COS_M   0.8775825618903728f  // cos(0.5)
#define SIN_M   0.479425538604203f   // sin(0.5)

__device__ __forceinline__ unsigned int f2bf1(float f) {
    unsigned int u = __float_as_uint(f);
    return (u + 0x7FFFu + ((u >> 16) & 1u)) >> 16;   // RNE
}
__device__ __forceinline__ unsigned int f2bf2(float lo, float hi) {
    return f2bf1(lo) | (f2bf1(hi) << 16);
}

// Fragment index within a 128-row x 16-chunk tile, matching the MFMA read pattern:
// idx = wn*1024 + j*256 + ks*64 + lk*16 + lr  where row = wn*64+j*16+lr, ck = ks*4+lk.

// Kernel 1: L2-normalize rows of x; write fp32 (target path) and bf16 in
// MFMA-B-fragment order (so k_main's B loads are fully coalesced).
// One block per 128-row tile; thread t owns row t>>1, k-half t&1.
__global__ __launch_bounds__(256)
void k_normalize(const float* __restrict__ x, float* __restrict__ xn,
                 uint4* __restrict__ xb2) {
    const int gt = blockIdx.x;        // row tile 0..15
    const int t = threadIdx.x;
    const int rr = t >> 1, h = t & 1;
    const int row = gt * 128 + rr;

    const f32x4* src = (const f32x4*)(x + (size_t)row * D_DIM + h * 64);
    f32x4 v[16];
    float s = 0.f;
    #pragma unroll
    for (int q = 0; q < 16; q++) {
        v[q] = src[q];
        s += v[q][0]*v[q][0] + v[q][1]*v[q][1] + v[q][2]*v[q][2] + v[q][3]*v[q][3];
    }
    s += __shfl_xor(s, 1);            // partner thread holds the other half of the row
    const float inv = 1.0f / sqrtf(s);

    f32x4* dxn = (f32x4*)(xn + (size_t)row * D_DIM + h * 64);
    #pragma unroll
    for (int q = 0; q < 16; q++) {
        v[q][0] *= inv; v[q][1] *= inv; v[q][2] *= inv; v[q][3] *= inv;
        dxn[q] = v[q];
    }

    const int wn = rr >> 6, j = (rr >> 4) & 3, lr = rr & 15;
    #pragma unroll
    for (int q2 = 0; q2 < 8; q2++) {
        const int ck = h * 8 + q2;
        const int ks = ck >> 2, lk = ck & 3;
        const int idx = gt * 2048 + wn * 1024 + j * 256 + ks * 64 + lk * 16 + lr;
        f32x4 f0 = v[q2 * 2], f1 = v[q2 * 2 + 1];
        xb2[idx] = make_uint4(f2bf2(f0[0], f0[1]), f2bf2(f0[2], f0[3]),
                              f2bf2(f1[0], f1[1]), f2bf2(f1[2], f1[3]));
    }
}

// Kernel 2: MFMA GEMM (A = W tile in LDS, fragment-ordered bf16; B = x from global,
// fragment-ordered, coalesced) fused with exp2 + per-x-row partial sums.
// One barrier total; no per-iteration syncs.
__global__ __launch_bounds__(256, 2)
void k_main(const uint4* __restrict__ xb2, const float* __restrict__ W,
            float* __restrict__ rowsum) {
    __shared__ uint4 Wsh[2048];       // 32 KB, fragment-ordered bf16 W tile
    const int t = threadIdx.x;
    const int c0 = blockIdx.y * 128;  // class tile base
    const int half = blockIdx.x;      // row half (0/1)

    // ---- stage + convert W tile, fragment order (once per block) ----
    #pragma unroll
    for (int m = 0; m < 8; m++) {
        const int idx = m * 256 + t;
        const int lr = idx & 15, lk = (idx >> 4) & 3;
        const int ks = (idx >> 6) & 3, fi = (idx >> 8) & 3, fwm = idx >> 10;
        const int cls = c0 + fwm * 64 + fi * 16 + lr;
        const int k0 = (ks * 4 + lk) * 8;
        uint4 val = make_uint4(0u, 0u, 0u, 0u);
        if (cls < N_CLS) {
            const f32x4* g = (const f32x4*)(W + (size_t)cls * D_DIM + k0);
            f32x4 f0 = g[0], f1 = g[1];
            val.x = f2bf2(f0[0], f0[1]); val.y = f2bf2(f0[2], f0[3]);
            val.z = f2bf2(f1[0], f1[1]); val.w = f2bf2(f1[2], f1[3]);
        }
        Wsh[idx] = val;
    }
    __syncthreads();

    const int lane = t & 63;
    const int wid = t >> 6;
    const int wm = wid >> 1;          // class half (0/1)
    const int wn = wid & 1;           // x-row half (0/1)
    const int lr = lane & 15;

    for (int it = 0; it < 8; it++) {
        const int r0 = half * 1024 + it * 128;
        const uint4* bsrc = xb2 + (size_t)(half * 8 + it) * 2048 + wn * 1024;

        // B fragments: 16 fully-coalesced 16B loads (L2-resident x)
        uint4 braw[4][4];             // [j][ks]
        #pragma unroll
        for (int j = 0; j < 4; j++)
            #pragma unroll
            for (int ks = 0; ks < 4; ks++)
                braw[j][ks] = bsrc[j * 256 + ks * 64 + lane];

        f32x4 acc[4][4];
        #pragma unroll
        for (int i = 0; i < 4; i++)
            #pragma unroll
            for (int j = 0; j < 4; j++)
                acc[i][j] = (f32x4){0.f, 0.f, 0.f, 0.f};

        #pragma unroll
        for (int ks = 0; ks < 4; ks++) {
            s16x8 a[4];
            #pragma unroll
            for (int i = 0; i < 4; i++)
                a[i] = *(const s16x8*)&Wsh[wm * 1024 + i * 256 + ks * 64 + lane];
            #pragma unroll
            for (int i = 0; i < 4; i++)
                #pragma unroll
                for (int j = 0; j < 4; j++)
                    acc[i][j] = __builtin_amdgcn_mfma_f32_16x16x32_bf16(
                        a[i], *(const s16x8*)&braw[j][ks], acc[i][j], 0, 0, 0);
        }

        // epilogue: D[class][xrow]; classes live in (regs x lk-groups), xrow in lr.
        #pragma unroll
        for (int j = 0; j < 4; j++) {
            float pj = 0.f;
            #pragma unroll
            for (int i = 0; i < 4; i++)
                #pragma unroll
                for (int r = 0; r < 4; r++)
                    pj += exp2f(S_LOG2E * acc[i][j][r]);
            pj += __shfl_xor(pj, 16);
            pj += __shfl_xor(pj, 32);
            if ((lane >> 4) == 0)
                atomicAdd(&rowsum[r0 + wn * 64 + j * 16 + lr], pj);
        }
    }
}

// Kernel 3: target logit wf[i, y_i] in fp32 (feeds the arccos margin path).
__global__ void k_tgt(const float* __restrict__ xn, const float* __restrict__ W,
                      const int* __restrict__ labels, float* __restrict__ tgt) {
    int row = blockIdx.x;
    int l = threadIdx.x;
    int y = labels[row];
    const float2* xr = reinterpret_cast<const float2*>(xn + (size_t)row * D_DIM);
    const float2* wr = reinterpret_cast<const float2*>(W + (size_t)y * D_DIM);
    float2 a = xr[l], b = wr[l];
    float s = a.x * b.x + a.y * b.y;
    #pragma unroll
    for (int off = 1; off < 64; off <<= 1) s += __shfl_xor(s, off);
    if (l == 0) tgt[row] = s;
}

// Kernel 4: per-row loss + mean. Single block. Subtracts the 96 pad-class exps.
__global__ void k_final(const float* __restrict__ rowsum, const float* __restrict__ tgt,
                        float* __restrict__ out) {
    int t = threadIdx.x;
    float lsum = 0.f;
    for (int i = t; i < N_ROWS; i += 256) {
        float tr = tgt[i];
        float tc = fminf(fmaxf(tr, -1.f + EPS_F), 1.f - EPS_F);
        float num = S_SCALE * (tc * COS_M - sqrtf(fmaxf(1.f - tc * tc, 0.f)) * SIN_M);
        float excl = rowsum[i] - N_PAD - __expf(S_SCALE * tr);
        float den = __expf(num) + excl;
        lsum += num - logf(den);
    }
    #pragma unroll
    for (int off = 1; off < 64; off <<= 1) lsum += __shfl_xor(lsum, off);
    __shared__ float wsums[4];
    if ((t & 63) == 0) wsums[t >> 6] = lsum;
    __syncthreads();
    if (t == 0) out[0] = -(wsums[0] + wsums[1] + wsums[2] + wsums[3]) / (float)N_ROWS;
}

extern "C" void kernel_launch(void* const* d_in, const int* in_sizes, int n_in,
                              void* d_out, int out_size, void* d_ws, size_t ws_size,
                              hipStream_t stream) {
    const float* x = (const float*)d_in[0];
    const float* W = (const float*)d_in[1];
    const int* labels = (const int*)d_in[2];
    float* out = (float*)d_out;

    float* xn     = (float*)d_ws;                                  // N*D fp32
    uint4* xb2    = (uint4*)(xn + (size_t)N_ROWS * D_DIM);         // N*D bf16, fragment order
    float* rowsum = (float*)((char*)xb2 + (size_t)N_ROWS * D_DIM * 2);
    float* tgt    = rowsum + N_ROWS;

    hipMemsetAsync(rowsum, 0, N_ROWS * sizeof(float), stream);
    k_normalize<<<N_ROWS / 128, 256, 0, stream>>>(x, xn, xb2);
    dim3 grid(2, N_TILES);
    k_main<<<grid, 256, 0, stream>>>(xb2, W, rowsum);
    k_tgt<<<N_ROWS, 64, 0, stream>>>(xn, W, labels, tgt);
    k_final<<<1, 256, 0, stream>>>(rowsum, tgt, out);
}

// Round 4
// 114.663 us; speedup vs baseline: 1.5544x; 1.5544x over previous
//
#include <hip/hip_runtime.h>
#include <math.h>

typedef __attribute__((ext_vector_type(8))) short s16x8;
typedef __attribute__((ext_vector_type(4))) float f32x4;

#define N_ROWS 2048
#define D_DIM  128
#define N_CLS  100000
#define N_TILES 782              // ceil(100000/128)
#define N_PAD   96.0f            // 782*128 - 100000 pad classes, each contributes exp(0)=1
#define S_SCALE 64.0f
#define S_LOG2E 92.33248261689366f   // 64 * log2(e)
#define EPS_F   1e-7f
#define COS_M   0.8775825618903728f  // cos(0.5)
#define SIN_M   0.479425538604203f   // sin(0.5)

#if __has_builtin(__builtin_amdgcn_exp2f)
#define EXP2F(x) __builtin_amdgcn_exp2f(x)
#else
#define EXP2F(x) exp2f(x)
#endif

__device__ __forceinline__ unsigned int f2bf1(float f) {
    unsigned int u = __float_as_uint(f);
    return (u + 0x7FFFu + ((u >> 16) & 1u)) >> 16;   // RNE
}
__device__ __forceinline__ unsigned int f2bf2(float lo, float hi) {
    return f2bf1(lo) | (f2bf1(hi) << 16);
}

// Kernel 1: L2-normalize rows of x; write fp32 (target path) and bf16 in
// MFMA-B-fragment order (so k_main's B loads are fully coalesced).
__global__ __launch_bounds__(256)
void k_normalize(const float* __restrict__ x, float* __restrict__ xn,
                 uint4* __restrict__ xb2) {
    const int gt = blockIdx.x;        // row tile 0..15
    const int t = threadIdx.x;
    const int rr = t >> 1, h = t & 1;
    const int row = gt * 128 + rr;

    const f32x4* src = (const f32x4*)(x + (size_t)row * D_DIM + h * 64);
    f32x4 v[16];
    float s = 0.f;
    #pragma unroll
    for (int q = 0; q < 16; q++) {
        v[q] = src[q];
        s += v[q][0]*v[q][0] + v[q][1]*v[q][1] + v[q][2]*v[q][2] + v[q][3]*v[q][3];
    }
    s += __shfl_xor(s, 1);            // partner thread holds the other half of the row
    const float inv = 1.0f / sqrtf(s);

    f32x4* dxn = (f32x4*)(xn + (size_t)row * D_DIM + h * 64);
    #pragma unroll
    for (int q = 0; q < 16; q++) {
        v[q][0] *= inv; v[q][1] *= inv; v[q][2] *= inv; v[q][3] *= inv;
        dxn[q] = v[q];
    }

    const int wn = rr >> 6, j = (rr >> 4) & 3, lr = rr & 15;
    #pragma unroll
    for (int q2 = 0; q2 < 8; q2++) {
        const int ck = h * 8 + q2;
        const int ks = ck >> 2, lk = ck & 3;
        const int idx = gt * 2048 + wn * 1024 + j * 256 + ks * 64 + lk * 16 + lr;
        f32x4 f0 = v[q2 * 2], f1 = v[q2 * 2 + 1];
        xb2[idx] = make_uint4(f2bf2(f0[0], f0[1]), f2bf2(f0[2], f0[3]),
                              f2bf2(f1[0], f1[1]), f2bf2(f1[2], f1[3]));
    }
}

// Kernel 2: MFMA GEMM (A = W tile in LDS, fragment-ordered bf16; B = x from global,
// fragment-ordered, coalesced) fused with exp2 + per-x-row partial sums.
// Partial sums accumulate in LDS; ONE atomic burst at block end (atomics never
// sit between loads and MFMA, so they can't pollute the vmcnt wait).
__global__ __launch_bounds__(256, 3)
void k_main(const uint4* __restrict__ xb2, const float* __restrict__ W,
            float* __restrict__ rowsum) {
    __shared__ uint4 Wsh[2048];        // 32 KB, fragment-ordered bf16 W tile
    __shared__ float psum[2][8][128];  // 8 KB: [wm][it][row-in-tile]
    const int t = threadIdx.x;
    const int c0 = blockIdx.y * 128;   // class tile base
    const int half = blockIdx.x;       // row half (0/1)

    // ---- stage + convert W tile, fragment order (once per block) ----
    #pragma unroll
    for (int m = 0; m < 8; m++) {
        const int idx = m * 256 + t;
        const int lr = idx & 15, lk = (idx >> 4) & 3;
        const int ks = (idx >> 6) & 3, fi = (idx >> 8) & 3, fwm = idx >> 10;
        const int cls = c0 + fwm * 64 + fi * 16 + lr;
        const int k0 = (ks * 4 + lk) * 8;
        uint4 val = make_uint4(0u, 0u, 0u, 0u);
        if (cls < N_CLS) {
            const f32x4* g = (const f32x4*)(W + (size_t)cls * D_DIM + k0);
            f32x4 f0 = g[0], f1 = g[1];
            val.x = f2bf2(f0[0], f0[1]); val.y = f2bf2(f0[2], f0[3]);
            val.z = f2bf2(f1[0], f1[1]); val.w = f2bf2(f1[2], f1[3]);
        }
        Wsh[idx] = val;
    }
    __syncthreads();

    const int lane = t & 63;
    const int wid = t >> 6;
    const int wm = wid >> 1;          // class half (0/1)
    const int wn = wid & 1;           // x-row half (0/1)
    const int lr = lane & 15;

    for (int it = 0; it < 8; it++) {
        const uint4* bsrc = xb2 + (size_t)(half * 8 + it) * 2048 + wn * 1024;

        // B fragments: 16 fully-coalesced 16B loads (L2-resident x)
        uint4 braw[4][4];             // [j][ks]
        #pragma unroll
        for (int j = 0; j < 4; j++)
            #pragma unroll
            for (int ks = 0; ks < 4; ks++)
                braw[j][ks] = bsrc[j * 256 + ks * 64 + lane];

        f32x4 acc[4][4];
        #pragma unroll
        for (int i = 0; i < 4; i++)
            #pragma unroll
            for (int j = 0; j < 4; j++)
                acc[i][j] = (f32x4){0.f, 0.f, 0.f, 0.f};

        #pragma unroll
        for (int ks = 0; ks < 4; ks++) {
            s16x8 a[4];
            #pragma unroll
            for (int i = 0; i < 4; i++)
                a[i] = *(const s16x8*)&Wsh[wm * 1024 + i * 256 + ks * 64 + lane];
            #pragma unroll
            for (int i = 0; i < 4; i++)
                #pragma unroll
                for (int j = 0; j < 4; j++)
                    acc[i][j] = __builtin_amdgcn_mfma_f32_16x16x32_bf16(
                        a[i], *(const s16x8*)&braw[j][ks], acc[i][j], 0, 0, 0);
        }

        // epilogue: D[class][xrow]; classes live in (regs x lk-groups), xrow in lr.
        #pragma unroll
        for (int j = 0; j < 4; j++) {
            float pj = 0.f;
            #pragma unroll
            for (int i = 0; i < 4; i++)
                #pragma unroll
                for (int r = 0; r < 4; r++)
                    pj += EXP2F(S_LOG2E * acc[i][j][r]);
            pj += __shfl_xor(pj, 16);
            pj += __shfl_xor(pj, 32);
            if ((lane >> 4) == 0)
                psum[wm][it][wn * 64 + j * 16 + lr] = pj;   // LDS, no vmcnt
        }
    }

    // ---- one atomic burst per block, after all compute ----
    __syncthreads();
    #pragma unroll
    for (int k = 0; k < 4; k++) {
        const int flat = t + k * 256;
        const int it = flat >> 7, r = flat & 127;
        const float v = psum[0][it][r] + psum[1][it][r];
        atomicAdd(&rowsum[half * 1024 + it * 128 + r], v);
    }
}

// Kernel 3: target logit wf[i, y_i] in fp32 (feeds the arccos margin path).
__global__ void k_tgt(const float* __restrict__ xn, const float* __restrict__ W,
                      const int* __restrict__ labels, float* __restrict__ tgt) {
    int row = blockIdx.x;
    int l = threadIdx.x;
    int y = labels[row];
    const float2* xr = reinterpret_cast<const float2*>(xn + (size_t)row * D_DIM);
    const float2* wr = reinterpret_cast<const float2*>(W + (size_t)y * D_DIM);
    float2 a = xr[l], b = wr[l];
    float s = a.x * b.x + a.y * b.y;
    #pragma unroll
    for (int off = 1; off < 64; off <<= 1) s += __shfl_xor(s, off);
    if (l == 0) tgt[row] = s;
}

// Kernel 4: per-row loss + mean. Single block. Subtracts the 96 pad-class exps.
__global__ void k_final(const float* __restrict__ rowsum, const float* __restrict__ tgt,
                        float* __restrict__ out) {
    int t = threadIdx.x;
    float lsum = 0.f;
    for (int i = t; i < N_ROWS; i += 256) {
        float tr = tgt[i];
        float tc = fminf(fmaxf(tr, -1.f + EPS_F), 1.f - EPS_F);
        float num = S_SCALE * (tc * COS_M - sqrtf(fmaxf(1.f - tc * tc, 0.f)) * SIN_M);
        float excl = rowsum[i] - N_PAD - __expf(S_SCALE * tr);
        float den = __expf(num) + excl;
        lsum += num - logf(den);
    }
    #pragma unroll
    for (int off = 1; off < 64; off <<= 1) lsum += __shfl_xor(lsum, off);
    __shared__ float wsums[4];
    if ((t & 63) == 0) wsums[t >> 6] = lsum;
    __syncthreads();
    if (t == 0) out[0] = -(wsums[0] + wsums[1] + wsums[2] + wsums[3]) / (float)N_ROWS;
}

extern "C" void kernel_launch(void* const* d_in, const int* in_sizes, int n_in,
                              void* d_out, int out_size, void* d_ws, size_t ws_size,
                              hipStream_t stream) {
    const float* x = (const float*)d_in[0];
    const float* W = (const float*)d_in[1];
    const int* labels = (const int*)d_in[2];
    float* out = (float*)d_out;

    float* xn     = (float*)d_ws;                                  // N*D fp32
    uint4* xb2    = (uint4*)(xn + (size_t)N_ROWS * D_DIM);         // N*D bf16, fragment order
    float* rowsum = (float*)((char*)xb2 + (size_t)N_ROWS * D_DIM * 2);
    float* tgt    = rowsum + N_ROWS;

    hipMemsetAsync(rowsum, 0, N_ROWS * sizeof(float), stream);
    k_normalize<<<N_ROWS / 128, 256, 0, stream>>>(x, xn, xb2);
    dim3 grid(2, N_TILES);
    k_main<<<grid, 256, 0, stream>>>(xb2, W, rowsum);
    k_tgt<<<N_ROWS, 64, 0, stream>>>(xn, W, labels, tgt);
    k_final<<<1, 256, 0, stream>>>(rowsum, tgt, out);
}

// Round 5
// 93.129 us; speedup vs baseline: 1.9138x; 1.2312x over previous
//
#include <hip/hip_runtime.h>
#include <math.h>

typedef __attribute__((ext_vector_type(8))) short s16x8;
typedef __attribute__((ext_vector_type(4))) float f32x4;

#define N_ROWS 2048
#define D_DIM  128
#define N_CLS  100000
#define N_TILES 782              // ceil(100000/128)
#define N_PAD   96.0f            // 782*128 - 100000 pad classes, each contributes exp(0)=1
#define S_SCALE 64.0f
#define S_LOG2E 92.33248261689366f   // 64 * log2(e)
#define EPS_F   1e-7f
#define COS_M   0.8775825618903728f  // cos(0.5)
#define SIN_M   0.479425538604203f   // sin(0.5)

#if __has_builtin(__builtin_amdgcn_exp2f)
#define EXP2F(x) __builtin_amdgcn_exp2f(x)
#else
#define EXP2F(x) exp2f(x)
#endif

__device__ __forceinline__ unsigned int f2bf1(float f) {
    unsigned int u = __float_as_uint(f);
    return (u + 0x7FFFu + ((u >> 16) & 1u)) >> 16;   // RNE
}
__device__ __forceinline__ unsigned int f2bf2(float lo, float hi) {
    return f2bf1(lo) | (f2bf1(hi) << 16);
}

// Kernel 1: L2-normalize rows of x -> bf16 in MFMA-B-fragment order, and
// (fused) target logit tgt[i] = xn[i] . W[labels[i]]. No fp32 xn buffer.
// 2 threads per row (h = k-half).
__global__ __launch_bounds__(256)
void k_normalize(const float* __restrict__ x, const float* __restrict__ W,
                 const int* __restrict__ labels,
                 float* __restrict__ tgt, uint4* __restrict__ xb2) {
    const int gt = blockIdx.x;        // row tile 0..15
    const int t = threadIdx.x;
    const int rr = t >> 1, h = t & 1;
    const int row = gt * 128 + rr;

    const f32x4* src = (const f32x4*)(x + (size_t)row * D_DIM + h * 64);
    f32x4 v[16];
    float s = 0.f;
    #pragma unroll
    for (int q = 0; q < 16; q++) {
        v[q] = src[q];
        s += v[q][0]*v[q][0] + v[q][1]*v[q][1] + v[q][2]*v[q][2] + v[q][3]*v[q][3];
    }
    s += __shfl_xor(s, 1);            // partner thread holds the other half of the row
    const float inv = 1.0f / sqrtf(s);

    // fused target-logit dot with W[y]
    const int y = labels[row];
    const f32x4* wsrc = (const f32x4*)(W + (size_t)y * D_DIM + h * 64);
    float d = 0.f;
    #pragma unroll
    for (int q = 0; q < 16; q++) {
        f32x4 w = wsrc[q];
        d += v[q][0]*w[0] + v[q][1]*w[1] + v[q][2]*w[2] + v[q][3]*w[3];
    }
    d += __shfl_xor(d, 1);
    if (h == 0) tgt[row] = d * inv;

    #pragma unroll
    for (int q = 0; q < 16; q++) {
        v[q][0] *= inv; v[q][1] *= inv; v[q][2] *= inv; v[q][3] *= inv;
    }

    const int wn = rr >> 6, j = (rr >> 4) & 3, lr = rr & 15;
    #pragma unroll
    for (int q2 = 0; q2 < 8; q2++) {
        const int ck = h * 8 + q2;
        const int ks = ck >> 2, lk = ck & 3;
        const int idx = gt * 2048 + wn * 1024 + j * 256 + ks * 64 + lk * 16 + lr;
        f32x4 f0 = v[q2 * 2], f1 = v[q2 * 2 + 1];
        xb2[idx] = make_uint4(f2bf2(f0[0], f0[1]), f2bf2(f0[2], f0[3]),
                              f2bf2(f1[0], f1[1]), f2bf2(f1[2], f1[3]));
    }
}

// One j-phase: prefetch next B fragment (static ping-pong buffers), 16 MFMA,
// per-phase exp epilogue into LDS psum. Static indexing throughout (rule #20).
#define PHASE(BCUR, BNEXT, IT, J, ITN, JN, LAST) do {                        \
    if (!(LAST)) {                                                            \
        _Pragma("unroll")                                                     \
        for (int ks_ = 0; ks_ < 4; ks_++)                                     \
            BNEXT[ks_] = bbase[(ITN) * 2048 + (JN) * 256 + ks_ * 64];         \
    }                                                                         \
    f32x4 acc0 = {0.f,0.f,0.f,0.f}, acc1 = {0.f,0.f,0.f,0.f};                 \
    f32x4 acc2 = {0.f,0.f,0.f,0.f}, acc3 = {0.f,0.f,0.f,0.f};                 \
    _Pragma("unroll")                                                         \
    for (int ks_ = 0; ks_ < 4; ks_++) {                                       \
        const s16x8 b_ = *(const s16x8*)&BCUR[ks_];                           \
        acc0 = __builtin_amdgcn_mfma_f32_16x16x32_bf16(a_[ks_][0], b_, acc0, 0, 0, 0); \
        acc1 = __builtin_amdgcn_mfma_f32_16x16x32_bf16(a_[ks_][1], b_, acc1, 0, 0, 0); \
        acc2 = __builtin_amdgcn_mfma_f32_16x16x32_bf16(a_[ks_][2], b_, acc2, 0, 0, 0); \
        acc3 = __builtin_amdgcn_mfma_f32_16x16x32_bf16(a_[ks_][3], b_, acc3, 0, 0, 0); \
    }                                                                         \
    float pj = 0.f;                                                           \
    _Pragma("unroll")                                                         \
    for (int r_ = 0; r_ < 4; r_++)                                            \
        pj += EXP2F(S_LOG2E * acc0[r_]) + EXP2F(S_LOG2E * acc1[r_])           \
            + EXP2F(S_LOG2E * acc2[r_]) + EXP2F(S_LOG2E * acc3[r_]);          \
    pj += __shfl_xor(pj, 16);                                                 \
    pj += __shfl_xor(pj, 32);                                                 \
    if ((lane >> 4) == 0)                                                     \
        psum[wm][IT][wn * 64 + (J) * 16 + lr] = pj;                           \
} while (0)

// Kernel 2: one block per 128-class tile; 16 row-tile iterations; j-granular
// software pipeline. Atomics only at block end.
__global__ __launch_bounds__(256, 3)
void k_main(const uint4* __restrict__ xb2, const float* __restrict__ W,
            float* __restrict__ rowsum) {
    __shared__ uint4 Wsh[2048];         // 32 KB, fragment-ordered bf16 W tile
    __shared__ float psum[2][16][128];  // 16 KB: [wm][it][row-in-tile]
    const int t = threadIdx.x;
    const int c0 = blockIdx.x * 128;    // class tile base

    // ---- stage + convert W tile, fragment order (once per block) ----
    #pragma unroll
    for (int m = 0; m < 8; m++) {
        const int idx = m * 256 + t;
        const int flr = idx & 15, lk = (idx >> 4) & 3;
        const int ks = (idx >> 6) & 3, fi = (idx >> 8) & 3, fwm = idx >> 10;
        const int cls = c0 + fwm * 64 + fi * 16 + flr;
        const int k0 = (ks * 4 + lk) * 8;
        uint4 val = make_uint4(0u, 0u, 0u, 0u);
        if (cls < N_CLS) {
            const f32x4* g = (const f32x4*)(W + (size_t)cls * D_DIM + k0);
            f32x4 f0 = g[0], f1 = g[1];
            val.x = f2bf2(f0[0], f0[1]); val.y = f2bf2(f0[2], f0[3]);
            val.z = f2bf2(f1[0], f1[1]); val.w = f2bf2(f1[2], f1[3]);
        }
        Wsh[idx] = val;
    }
    __syncthreads();

    const int lane = t & 63;
    const int wid = t >> 6;
    const int wm = wid >> 1;            // class half (0/1)
    const int wn = wid & 1;             // x-row half (0/1)
    const int lr = lane & 15;
    const uint4* bbase = xb2 + wn * 1024 + lane;

    uint4 bA[4], bB[4];
    s16x8 a_[4][4];

    // prologue: B fragment for (it=0, j=0)
    #pragma unroll
    for (int ks = 0; ks < 4; ks++) bA[ks] = bbase[ks * 64];

    for (int it = 0; it < 16; it++) {
        #pragma unroll
        for (int ks = 0; ks < 4; ks++)
            #pragma unroll
            for (int i = 0; i < 4; i++)
                a_[ks][i] = *(const s16x8*)&Wsh[wm * 1024 + i * 256 + ks * 64 + lane];
        PHASE(bA, bB, it, 0, it, 1, false);
        PHASE(bB, bA, it, 1, it, 2, false);
        PHASE(bA, bB, it, 2, it, 3, false);
        PHASE(bB, bA, it, 3, it + 1, 0, it == 15);
    }

    // ---- one atomic burst per block, after all compute ----
    __syncthreads();
    #pragma unroll
    for (int k = 0; k < 8; k++) {
        const int flat = t + k * 256;
        const int it = flat >> 7, r = flat & 127;
        atomicAdd(&rowsum[it * 128 + r], psum[0][it][r] + psum[1][it][r]);
    }
}

// Kernel 3: per-row loss + mean. Single block. Subtracts the 96 pad-class exps.
__global__ void k_final(const float* __restrict__ rowsum, const float* __restrict__ tgt,
                        float* __restrict__ out) {
    int t = threadIdx.x;
    float lsum = 0.f;
    for (int i = t; i < N_ROWS; i += 256) {
        float tr = tgt[i];
        float tc = fminf(fmaxf(tr, -1.f + EPS_F), 1.f - EPS_F);
        float num = S_SCALE * (tc * COS_M - sqrtf(fmaxf(1.f - tc * tc, 0.f)) * SIN_M);
        float excl = rowsum[i] - N_PAD - __expf(S_SCALE * tr);
        float den = __expf(num) + excl;
        lsum += num - logf(den);
    }
    #pragma unroll
    for (int off = 1; off < 64; off <<= 1) lsum += __shfl_xor(lsum, off);
    __shared__ float wsums[4];
    if ((t & 63) == 0) wsums[t >> 6] = lsum;
    __syncthreads();
    if (t == 0) out[0] = -(wsums[0] + wsums[1] + wsums[2] + wsums[3]) / (float)N_ROWS;
}

extern "C" void kernel_launch(void* const* d_in, const int* in_sizes, int n_in,
                              void* d_out, int out_size, void* d_ws, size_t ws_size,
                              hipStream_t stream) {
    const float* x = (const float*)d_in[0];
    const float* W = (const float*)d_in[1];
    const int* labels = (const int*)d_in[2];
    float* out = (float*)d_out;

    uint4* xb2    = (uint4*)d_ws;                                   // N*D bf16, fragment order
    float* rowsum = (float*)((char*)xb2 + (size_t)N_ROWS * D_DIM * 2);
    float* tgt    = rowsum + N_ROWS;

    hipMemsetAsync(rowsum, 0, N_ROWS * sizeof(float), stream);
    k_normalize<<<N_ROWS / 128, 256, 0, stream>>>(x, W, labels, tgt, xb2);
    k_main<<<N_TILES, 256, 0, stream>>>(xb2, W, rowsum);
    k_final<<<1, 256, 0, stream>>>(rowsum, tgt, out);
}